// Round 5
// baseline (7855.823 us; speedup 1.0000x reference)
//
#include <hip/hip_runtime.h>
#include <hip/hip_bf16.h>
#include <stdint.h>

// Decoder: 2-layer LSTM, B=2048, T=96, H=1024, teacher forcing=1.0.
// Round 5: 256x256 phased GEMM (4 quadrant-phases/K-tile, BK=64, 512 thr,
// 8 waves of 128x64, 128KB LDS, both-sides XOR swizzle, setprio, counted-
// distance vmcnt). D_t = {L2(t) || L1(t+1)}, grid 256 = 1 block/CU.

#define BB  2048
#define TT  96
#define NG  4096
#define KL1 1088      // 64 (x pad) + 1024 (h1)
#define KL2 2048      // h1 | h2

typedef __bf16 bf16;
typedef __bf16 bf16x8 __attribute__((ext_vector_type(8)));
typedef float  f32x4  __attribute__((ext_vector_type(4)));

__device__ __forceinline__ float sigm(float x) { return 1.0f / (1.0f + __expf(-x)); }

__device__ __forceinline__ void gload16(const bf16* g, bf16* l) {
  __builtin_amdgcn_global_load_lds((const __attribute__((address_space(1))) void*)g,
                                   (__attribute__((address_space(3))) void*)l, 16, 0, 0);
}

#define SB()  __builtin_amdgcn_sched_barrier(0)
#define BAR() __builtin_amdgcn_s_barrier()
#define WAITV0() asm volatile("s_waitcnt vmcnt(0)" ::: "memory")
#define WAITL0() asm volatile("s_waitcnt lgkmcnt(0)" ::: "memory")

// ---------------- prep kernels ----------------
// Weight rows permuted: out row n' = h*4 + gate  <-  in row gate*1024 + h.

__global__ __launch_bounds__(256) void build_w0(const float* __restrict__ Wih0,
                                                const float* __restrict__ Whh0,
                                                bf16* __restrict__ W0) {
  int idx = blockIdx.x * 256 + threadIdx.x;
  if (idx >= NG * KL1) return;
  int np = idx / KL1, k = idx % KL1;
  int n = (np & 3) * 1024 + (np >> 2);
  float v;
  if (k < 60)       v = Wih0[n * 60 + k];
  else if (k < 64)  v = 0.0f;
  else              v = Whh0[n * 1024 + (k - 64)];
  W0[idx] = (bf16)v;
}

__global__ __launch_bounds__(256) void build_w1(const float* __restrict__ Wih1,
                                                const float* __restrict__ Whh1,
                                                bf16* __restrict__ W1) {
  int idx = blockIdx.x * 256 + threadIdx.x;
  if (idx >= NG * KL2) return;
  int np = idx >> 11, k = idx & 2047;
  int n = (np & 3) * 1024 + (np >> 2);
  float v = (k < 1024) ? Wih1[n * 1024 + k] : Whh1[n * 1024 + (k - 1024)];
  W1[idx] = (bf16)v;
}

__global__ __launch_bounds__(256) void perm_bias(const float* __restrict__ b0,
                                                 const float* __restrict__ b1,
                                                 float* __restrict__ b0p,
                                                 float* __restrict__ b1p) {
  int idx = blockIdx.x * 256 + threadIdx.x;
  if (idx >= NG) return;
  int n = (idx & 3) * 1024 + (idx >> 2);
  b0p[idx] = b0[n];
  b1p[idx] = b1[n];
}

// X2 layout: [t][b][64]  (so A rows for fixed t are stride-64, coalesced)
__global__ __launch_bounds__(256) void build_x2(
    const float* __restrict__ dec, const float* __restrict__ ty, const float* __restrict__ lec,
    const int* __restrict__ gid, const int* __restrict__ cp, const int* __restrict__ cct,
    const int* __restrict__ cpt, const int* __restrict__ ccl,
    const float* __restrict__ gemb, const float* __restrict__ ep, const float* __restrict__ ect,
    const float* __restrict__ ept, const float* __restrict__ ecl,
    bf16* __restrict__ X2) {
  int idx = blockIdx.x * 256 + threadIdx.x;  // over T*B
  if (idx >= BB * TT) return;
  int t = idx >> 11, b = idx & 2047;
  bf16* x = X2 + (size_t)idx * 64;
  x[0] = (bf16)((t == 0) ? lec[b] : ty[b * TT + t - 1]);
  const float* d = dec + ((size_t)b * TT + t) * 32;
  #pragma unroll
  for (int k = 0; k < 32; ++k) x[1 + k] = (bf16)d[k];
  const float* e;
  e = ep  + cp[b]  * 4;  for (int j = 0; j < 4;  ++j) x[33 + j] = (bf16)e[j];
  e = ect + cct[b] * 2;  for (int j = 0; j < 2;  ++j) x[37 + j] = (bf16)e[j];
  e = ept + cpt[b] * 3;  for (int j = 0; j < 3;  ++j) x[39 + j] = (bf16)e[j];
  e = ecl + ccl[b] * 2;  for (int j = 0; j < 2;  ++j) x[42 + j] = (bf16)e[j];
  e = gemb + gid[b] * 16; for (int j = 0; j < 16; ++j) x[44 + j] = (bf16)e[j];
  for (int j = 60; j < 64; ++j) x[j] = (bf16)0.0f;
}

__global__ __launch_bounds__(256) void init_state(const float* __restrict__ enc_h,
                                                  const float* __restrict__ enc_c,
                                                  bf16* __restrict__ H1b,
                                                  bf16* __restrict__ H2b,
                                                  float* __restrict__ c1t,
                                                  float* __restrict__ c2t) {
  int idx = blockIdx.x * 256 + threadIdx.x;  // over B*H
  if (idx >= BB * 1024) return;
  int b = idx >> 10, h = idx & 1023;
  H1b[idx] = (bf16)enc_h[idx];
  H2b[idx] = (bf16)enc_h[(size_t)BB * 1024 + idx];
  c1t[(size_t)h * BB + b] = enc_c[idx];
  c2t[(size_t)h * BB + b] = enc_c[(size_t)BB * 1024 + idx];
}

// ---------------- 256x256 phased GEMM + fused cell ----------------
// gates(b, n') = A(b,:) . W(n',:), n' = h*4 + gate (gate-interleaved weights).
// mfma(W_frag, A_frag): D col = batch (lane&15), D row = u*4+reg -> lane's
// f32x4 = {i,f,g,o} of one (b,h) cell.
// Wave w: gate quarter wq=w&3 (64 gates), batch half wbh=w>>2 (128 batch).
// LDS per operand: [2 dbuf][2 half][128 rows][64 k] bf16 = 64KB; A+W = 128KB.
// Swizzle: LDS[r][slot] = G[r][slot ^ (r&7)] (16B slots), both sides.

template <int MODE>  // 0: L1 (K=1088, A=[x|h1], writes h1)  1: L2 (K=2048, A=[h1|h2], +proj)
__device__ __forceinline__ void gemm_body(
    int tm, int tn, int t,
    const bf16* __restrict__ P0, const bf16* __restrict__ P1,
    const bf16* __restrict__ Wt, const float* __restrict__ bperm,
    float* __restrict__ ct, bf16* __restrict__ Hout,
    const float* __restrict__ wp, const float* __restrict__ bp,
    float* __restrict__ y,
    bf16* Al, bf16* Wl)
{
  constexpr int KT = (MODE == 0) ? KL1 : KL2;
  constexpr int NT = KT / 64;

  const int tid = threadIdx.x;
  const int lane = tid & 63, w = tid >> 6;
  const int l15 = lane & 15, u = lane >> 4;
  const int wq = w & 3, wbh = w >> 2;

  f32x4 acc[8][4];
  #pragma unroll
  for (int i = 0; i < 8; ++i)
    #pragma unroll
    for (int j = 0; j < 4; ++j) acc[i][j] = (f32x4){0.f, 0.f, 0.f, 0.f};

  // staging geometry
  const int srow = w * 8 + (lane >> 3);           // row within 128-half (+64 for 2nd load)
  const int kx   = (lane & 7) ^ (srow & 7);       // swizzled source 16B-slot
  const int dA   = w * 512 + lane * 8;            // LDS elem offset within half region
  // read geometry (elem offsets of swizzled 16B slot)
  const int jx0 = ((u     ) ^ (l15 & 7)) << 3;    // ks=0
  const int jx1 = ((4 + u ) ^ (l15 & 7)) << 3;    // ks=1

  auto asrc = [&](int row, int kt) -> const bf16* {
    if constexpr (MODE == 0) {
      if (kt == 0) return P0 + (size_t)(tm + row) * 64 + kx * 8;
      return P1 + (size_t)(tm + row) * 1024 + (kt - 1) * 64 + kx * 8;
    } else {
      if (kt < 16) return P0 + (size_t)(tm + row) * 1024 + kt * 64 + kx * 8;
      return P1 + (size_t)(tm + row) * 1024 + (kt - 16) * 64 + kx * 8;
    }
  };
  auto stageA = [&](int buf, int half, int kt) {
    bf16* base = Al + (buf * 2 + half) * 8192;
    gload16(asrc(half * 128 + srow, kt),      base + dA);
    gload16(asrc(half * 128 + srow + 64, kt), base + dA + 4096);
  };
  auto stageW = [&](int buf, int half, int kt) {
    bf16* base = Wl + (buf * 2 + half) * 8192;
    const bf16* g0 = Wt + (size_t)(tn + half * 128 + srow) * KT + kt * 64 + kx * 8;
    const bf16* g1 = Wt + (size_t)(tn + half * 128 + srow + 64) * KT + kt * 64 + kx * 8;
    gload16(g0, base + dA);
    gload16(g1, base + dA + 4096);
  };
  auto rdA = [&](int buf, int bf, int ks) -> bf16x8 {
    return *reinterpret_cast<const bf16x8*>(
        Al + (buf * 2 + wbh) * 8192 + (bf * 16 + l15) * 64 + (ks ? jx1 : jx0));
  };
  auto rdW = [&](int buf, int gf, int ks) -> bf16x8 {
    return *reinterpret_cast<const bf16x8*>(
        Wl + (buf * 2 + (wq >> 1)) * 8192 + ((wq & 1) * 64 + gf * 16 + l15) * 64 + (ks ? jx1 : jx0));
  };

  // prologue: stage K-tile 0 into buf 0 (8 loads/thread in flight)
  stageA(0, 0, 0); stageA(0, 1, 0); stageW(0, 0, 0); stageW(0, 1, 0);

  bf16x8 a_[8], w0_[4], w1_[4];

  for (int kt = 0; kt < NT; ++kt) {
    const int buf = kt & 1, nbuf = buf ^ 1;
    const bool pre = (kt + 1 < NT);

    // flip: loads for this tile were issued >= 4 phases ago
    WAITV0(); SB(); BAR(); SB();
    if (pre) { stageA(nbuf, 0, kt + 1); stageA(nbuf, 1, kt + 1); }

    // phase 1: quadrant (bh0, gh0)
    #pragma unroll
    for (int bf = 0; bf < 4; ++bf) { a_[bf * 2] = rdA(buf, bf, 0); a_[bf * 2 + 1] = rdA(buf, bf, 1); }
    #pragma unroll
    for (int g = 0; g < 2; ++g) { w0_[g * 2] = rdW(buf, g, 0); w0_[g * 2 + 1] = rdW(buf, g, 1); }
    if (pre) stageW(nbuf, 0, kt + 1);
    SB(); BAR();
    WAITL0(); SB();
    __builtin_amdgcn_s_setprio(1);
    #pragma unroll
    for (int bf = 0; bf < 4; ++bf)
      #pragma unroll
      for (int g = 0; g < 2; ++g)
        #pragma unroll
        for (int ks = 0; ks < 2; ++ks)
          acc[bf][g] = __builtin_amdgcn_mfma_f32_16x16x32_bf16(w0_[g * 2 + ks], a_[bf * 2 + ks], acc[bf][g], 0, 0, 0);
    __builtin_amdgcn_s_setprio(0);
    SB(); BAR();

    // phase 2: quadrant (bh0, gh1)
    #pragma unroll
    for (int g = 0; g < 2; ++g) { w1_[g * 2] = rdW(buf, 2 + g, 0); w1_[g * 2 + 1] = rdW(buf, 2 + g, 1); }
    if (pre) stageW(nbuf, 1, kt + 1);
    SB(); BAR();
    WAITL0(); SB();
    __builtin_amdgcn_s_setprio(1);
    #pragma unroll
    for (int bf = 0; bf < 4; ++bf)
      #pragma unroll
      for (int g = 0; g < 2; ++g)
        #pragma unroll
        for (int ks = 0; ks < 2; ++ks)
          acc[bf][2 + g] = __builtin_amdgcn_mfma_f32_16x16x32_bf16(w1_[g * 2 + ks], a_[bf * 2 + ks], acc[bf][2 + g], 0, 0, 0);
    __builtin_amdgcn_s_setprio(0);
    SB(); BAR();

    // phase 3: quadrant (bh1, gh1)
    #pragma unroll
    for (int bf = 0; bf < 4; ++bf) { a_[bf * 2] = rdA(buf, 4 + bf, 0); a_[bf * 2 + 1] = rdA(buf, 4 + bf, 1); }
    SB(); BAR();
    WAITL0(); SB();
    __builtin_amdgcn_s_setprio(1);
    #pragma unroll
    for (int bf = 0; bf < 4; ++bf)
      #pragma unroll
      for (int g = 0; g < 2; ++g)
        #pragma unroll
        for (int ks = 0; ks < 2; ++ks)
          acc[4 + bf][2 + g] = __builtin_amdgcn_mfma_f32_16x16x32_bf16(w1_[g * 2 + ks], a_[bf * 2 + ks], acc[4 + bf][2 + g], 0, 0, 0);
    __builtin_amdgcn_s_setprio(0);
    SB(); BAR();

    // phase 4: quadrant (bh1, gh0) — no reads, w0_ held
    __builtin_amdgcn_s_setprio(1);
    #pragma unroll
    for (int bf = 0; bf < 4; ++bf)
      #pragma unroll
      for (int g = 0; g < 2; ++g)
        #pragma unroll
        for (int ks = 0; ks < 2; ++ks)
          acc[4 + bf][g] = __builtin_amdgcn_mfma_f32_16x16x32_bf16(w0_[g * 2 + ks], a_[bf * 2 + ks], acc[4 + bf][g], 0, 0, 0);
    __builtin_amdgcn_s_setprio(0);
    // no end barrier: flip barrier of next tile serves
  }

  SB(); BAR(); SB();   // all K-loop LDS reads done -> safe to reuse LDS

  // ---- fused cell epilogue ----
  bf16* hst = Al + w * 3072;          // per-wave [128 batch][24-padded 16 h] bf16
  const int hb = (tn >> 2) + wq * 16; // wave's h base (16 h values)
  const int bgb = tm + wbh * 128;     // wave's batch base
  float yp[8] = {0.f, 0.f, 0.f, 0.f, 0.f, 0.f, 0.f, 0.f};

  #pragma unroll
  for (int gf = 0; gf < 4; ++gf) {
    int hg = hb + gf * 4 + u;
    f32x4 bv = *reinterpret_cast<const f32x4*>(&bperm[hg * 4]);
    float wph = 0.f;
    if constexpr (MODE == 1) wph = wp[hg];
    #pragma unroll
    for (int bf = 0; bf < 8; ++bf) {
      int bg = bgb + bf * 16 + l15;
      float gi = acc[bf][gf][0] + bv[0];
      float gf_ = acc[bf][gf][1] + bv[1];
      float gg = acc[bf][gf][2] + bv[2];
      float go = acc[bf][gf][3] + bv[3];
      float* cp_ = ct + (size_t)hg * BB + bg;
      float c = *cp_;
      float cn = sigm(gf_) * c + sigm(gi) * tanhf(gg);
      float hn = sigm(go) * tanhf(cn);
      *cp_ = cn;
      hst[(bf * 16 + l15) * 24 + gf * 4 + u] = (bf16)hn;
      if constexpr (MODE == 1) yp[bf] += hn * wph;
    }
  }

  WAITL0(); SB();

  // coalesced H write: wave patch = 128 batch x 16 h
  #pragma unroll
  for (int q = 0; q < 4; ++q) {
    int chunk = q * 64 + lane;        // 0..255
    int row = chunk >> 1, half8 = chunk & 1;
    bf16x8 v = *reinterpret_cast<const bf16x8*>(&hst[row * 24 + half8 * 8]);
    *reinterpret_cast<bf16x8*>(&Hout[(size_t)(bgb + row) * 1024 + hb + half8 * 8]) = v;
  }

  if constexpr (MODE == 1) {
    #pragma unroll
    for (int bf = 0; bf < 8; ++bf) {
      float s = yp[bf];
      s += __shfl_xor(s, 16);
      s += __shfl_xor(s, 32);
      if (lane < 16)
        atomicAdd(&y[(size_t)(bgb + bf * 16 + lane) * TT + t], s);
    }
  } else {
    // init y[:, t] = b_proj (blocks with tn==0 cover all batches)
    if (tn == 0 && tid < 256) y[(size_t)(tm + tid) * TT + t] = bp[0];
  }
}

// Combined dispatch: 256 blocks. XCD-grouped decode so each XCD's L2 caches
// only 2 W-panels: x=bid&7, i=bid>>3: mode=i&1, tm=i>>2, tn = x*2 + ((i>>1)&1).
__global__ __launch_bounds__(512, 2) void step256(
    const bf16* __restrict__ H1in, const bf16* __restrict__ H2in,
    bf16* __restrict__ H1out, bf16* __restrict__ H2out,
    const bf16* __restrict__ X2,
    const bf16* __restrict__ W0, const bf16* __restrict__ W1,
    const float* __restrict__ b0p, const float* __restrict__ b1p,
    float* __restrict__ c1t, float* __restrict__ c2t,
    const float* __restrict__ wp, const float* __restrict__ bp,
    float* __restrict__ y, int t2, int all_l1) {
  __shared__ alignas(16) bf16 Al[32768];
  __shared__ alignas(16) bf16 Wl[32768];
  int bid = (int)blockIdx.x;
  int mode, tmx, tnx;
  if (all_l1) { mode = 0; tmx = bid >> 4; tnx = bid & 15; }
  else {
    int x = bid & 7, i = bid >> 3;
    mode = i & 1; tmx = i >> 2; tnx = x * 2 + ((i >> 1) & 1);
  }
  if (mode == 0) {
    int t1 = t2 + 1;
    if (t1 >= TT) return;
    gemm_body<0>(tmx * 256, tnx * 256, t1, X2 + (size_t)t1 * 2048 * 64, H1in,
                 W0, b0p, c1t, H1out, nullptr, bp, y, Al, Wl);
  } else {
    gemm_body<1>(tmx * 256, tnx * 256, t2, H1in, H2in,
                 W1, b1p, c2t, H2out, wp, nullptr, y, Al, Wl);
  }
}

// ---------------- launch ----------------

extern "C" void kernel_launch(void* const* d_in, const int* in_sizes, int n_in,
                              void* d_out, int out_size, void* d_ws, size_t ws_size,
                              hipStream_t stream) {
  const float* dec   = (const float*)d_in[0];
  const float* ty    = (const float*)d_in[1];
  const float* enc_h = (const float*)d_in[2];
  const float* enc_c = (const float*)d_in[3];
  const float* lec   = (const float*)d_in[4];
  const int*   gid   = (const int*)d_in[5];
  const int*   cp    = (const int*)d_in[6];
  const int*   cct   = (const int*)d_in[7];
  const int*   cpt   = (const int*)d_in[8];
  const int*   ccl   = (const int*)d_in[9];
  const float* gemb  = (const float*)d_in[10];
  const float* ep    = (const float*)d_in[11];
  const float* ect   = (const float*)d_in[12];
  const float* ept   = (const float*)d_in[13];
  const float* ecl   = (const float*)d_in[14];
  const float* Wih0  = (const float*)d_in[15];
  const float* Whh0  = (const float*)d_in[16];
  const float* b0    = (const float*)d_in[17];
  const float* Wih1  = (const float*)d_in[18];
  const float* Whh1  = (const float*)d_in[19];
  const float* b1    = (const float*)d_in[20];
  const float* wp    = (const float*)d_in[21];
  const float* bp    = (const float*)d_in[22];
  float* y = (float*)d_out;

  char* ws = (char*)d_ws;
  bf16* W0    = (bf16*)ws;  ws += (size_t)NG * KL1 * 2;      //  8.9 MB
  bf16* W1    = (bf16*)ws;  ws += (size_t)NG * KL2 * 2;      // 16.8 MB
  bf16* X2    = (bf16*)ws;  ws += (size_t)BB * TT * 64 * 2;  // 25.2 MB  [t][b][64]
  bf16* H1a   = (bf16*)ws;  ws += (size_t)BB * 1024 * 2;     //  4.2 MB
  bf16* H1b   = (bf16*)ws;  ws += (size_t)BB * 1024 * 2;
  bf16* H2a   = (bf16*)ws;  ws += (size_t)BB * 1024 * 2;
  bf16* H2b   = (bf16*)ws;  ws += (size_t)BB * 1024 * 2;
  float* c1t  = (float*)ws; ws += (size_t)BB * 1024 * 4;     //  8.4 MB
  float* c2t  = (float*)ws; ws += (size_t)BB * 1024 * 4;     //  8.4 MB
  float* b0p  = (float*)ws; ws += (size_t)NG * 4;
  float* b1p  = (float*)ws; ws += (size_t)NG * 4;

  build_w0<<<(NG * KL1 + 255) / 256, 256, 0, stream>>>(Wih0, Whh0, W0);
  build_w1<<<(NG * KL2 + 255) / 256, 256, 0, stream>>>(Wih1, Whh1, W1);
  perm_bias<<<NG / 256, 256, 0, stream>>>(b0, b1, b0p, b1p);
  build_x2<<<(BB * TT + 255) / 256, 256, 0, stream>>>(dec, ty, lec, gid, cp, cct, cpt, ccl,
                                                      gemb, ep, ect, ept, ecl, X2);
  init_state<<<(BB * 1024) / 256, 256, 0, stream>>>(enc_h, enc_c, H1b, H2b, c1t, c2t);

  // prologue: L1(0) alone (grid 128). h1(t) in H1[t&1]; h2(t) in H2[t&1].
  step256<<<128, 512, 0, stream>>>(H1b, nullptr, H1a, nullptr, X2, W0, W1,
                                   b0p, b1p, c1t, c2t, wp, bp, y, -1, 1);
  for (int t = 0; t < TT; ++t) {
    bf16* h1i = (t & 1) ? H1b : H1a;
    bf16* h1o = (t & 1) ? H1a : H1b;
    bf16* h2i = (t & 1) ? H2a : H2b;
    bf16* h2o = (t & 1) ? H2b : H2a;
    step256<<<256, 512, 0, stream>>>(h1i, h2i, h1o, h2o, X2, W0, W1,
                                     b0p, b1p, c1t, c2t, wp, bp, y, t, 0);
  }
}

// Round 6
// 7579.691 us; speedup vs baseline: 1.0364x; 1.0364x over previous
//
#include <hip/hip_runtime.h>
#include <hip/hip_bf16.h>
#include <stdint.h>

// Decoder: 2-layer LSTM, B=2048, T=96, H=1024, teacher forcing=1.0.
// Round 6: 256x256 tile, BK=64, 512 thr (8 waves of 128x64). ONE barrier per
// K-tile: [vmcnt(0); bar; stage all 8 loads of next tile; 4 quadrant MFMA
// clusters, compiler-scheduled lgkm]. Loads get a full tile (~620cyc) of cover.
// D_t = {L2(t) || L1(t+1)}, grid 256, XCD-grouped tn.

#define BB  2048
#define TT  96
#define NG  4096
#define KL1 1088      // 64 (x pad) + 1024 (h1)
#define KL2 2048      // h1 | h2

typedef __bf16 bf16;
typedef __bf16 bf16x8 __attribute__((ext_vector_type(8)));
typedef float  f32x4  __attribute__((ext_vector_type(4)));

__device__ __forceinline__ float sigm(float x) { return 1.0f / (1.0f + __expf(-x)); }

__device__ __forceinline__ void gload16(const bf16* g, bf16* l) {
  __builtin_amdgcn_global_load_lds((const __attribute__((address_space(1))) void*)g,
                                   (__attribute__((address_space(3))) void*)l, 16, 0, 0);
}

#define SB()  __builtin_amdgcn_sched_barrier(0)
#define BAR() __builtin_amdgcn_s_barrier()
#define WAITV0() asm volatile("s_waitcnt vmcnt(0)" ::: "memory")
#define WAITL0() asm volatile("s_waitcnt lgkmcnt(0)" ::: "memory")

// ---------------- prep kernels ----------------
// Weight rows permuted: out row n' = h*4 + gate  <-  in row gate*1024 + h.

__global__ __launch_bounds__(256) void build_w0(const float* __restrict__ Wih0,
                                                const float* __restrict__ Whh0,
                                                bf16* __restrict__ W0) {
  int idx = blockIdx.x * 256 + threadIdx.x;
  if (idx >= NG * KL1) return;
  int np = idx / KL1, k = idx % KL1;
  int n = (np & 3) * 1024 + (np >> 2);
  float v;
  if (k < 60)       v = Wih0[n * 60 + k];
  else if (k < 64)  v = 0.0f;
  else              v = Whh0[n * 1024 + (k - 64)];
  W0[idx] = (bf16)v;
}

__global__ __launch_bounds__(256) void build_w1(const float* __restrict__ Wih1,
                                                const float* __restrict__ Whh1,
                                                bf16* __restrict__ W1) {
  int idx = blockIdx.x * 256 + threadIdx.x;
  if (idx >= NG * KL2) return;
  int np = idx >> 11, k = idx & 2047;
  int n = (np & 3) * 1024 + (np >> 2);
  float v = (k < 1024) ? Wih1[n * 1024 + k] : Whh1[n * 1024 + (k - 1024)];
  W1[idx] = (bf16)v;
}

__global__ __launch_bounds__(256) void perm_bias(const float* __restrict__ b0,
                                                 const float* __restrict__ b1,
                                                 float* __restrict__ b0p,
                                                 float* __restrict__ b1p) {
  int idx = blockIdx.x * 256 + threadIdx.x;
  if (idx >= NG) return;
  int n = (idx & 3) * 1024 + (idx >> 2);
  b0p[idx] = b0[n];
  b1p[idx] = b1[n];
}

// X2 layout: [t][b][64]
__global__ __launch_bounds__(256) void build_x2(
    const float* __restrict__ dec, const float* __restrict__ ty, const float* __restrict__ lec,
    const int* __restrict__ gid, const int* __restrict__ cp, const int* __restrict__ cct,
    const int* __restrict__ cpt, const int* __restrict__ ccl,
    const float* __restrict__ gemb, const float* __restrict__ ep, const float* __restrict__ ect,
    const float* __restrict__ ept, const float* __restrict__ ecl,
    bf16* __restrict__ X2) {
  int idx = blockIdx.x * 256 + threadIdx.x;  // over T*B
  if (idx >= BB * TT) return;
  int t = idx >> 11, b = idx & 2047;
  bf16* x = X2 + (size_t)idx * 64;
  x[0] = (bf16)((t == 0) ? lec[b] : ty[b * TT + t - 1]);
  const float* d = dec + ((size_t)b * TT + t) * 32;
  #pragma unroll
  for (int k = 0; k < 32; ++k) x[1 + k] = (bf16)d[k];
  const float* e;
  e = ep  + cp[b]  * 4;  for (int j = 0; j < 4;  ++j) x[33 + j] = (bf16)e[j];
  e = ect + cct[b] * 2;  for (int j = 0; j < 2;  ++j) x[37 + j] = (bf16)e[j];
  e = ept + cpt[b] * 3;  for (int j = 0; j < 3;  ++j) x[39 + j] = (bf16)e[j];
  e = ecl + ccl[b] * 2;  for (int j = 0; j < 2;  ++j) x[42 + j] = (bf16)e[j];
  e = gemb + gid[b] * 16; for (int j = 0; j < 16; ++j) x[44 + j] = (bf16)e[j];
  for (int j = 60; j < 64; ++j) x[j] = (bf16)0.0f;
}

__global__ __launch_bounds__(256) void init_state(const float* __restrict__ enc_h,
                                                  const float* __restrict__ enc_c,
                                                  bf16* __restrict__ H1b,
                                                  bf16* __restrict__ H2b,
                                                  float* __restrict__ c1t,
                                                  float* __restrict__ c2t) {
  int idx = blockIdx.x * 256 + threadIdx.x;  // over B*H
  if (idx >= BB * 1024) return;
  int b = idx >> 10, h = idx & 1023;
  H1b[idx] = (bf16)enc_h[idx];
  H2b[idx] = (bf16)enc_h[(size_t)BB * 1024 + idx];
  c1t[(size_t)h * BB + b] = enc_c[idx];
  c2t[(size_t)h * BB + b] = enc_c[(size_t)BB * 1024 + idx];
}

// ---------------- 256x256 GEMM + fused cell ----------------
// gates(b, n') = A(b,:) . W(n',:), n' = h*4 + gate (gate-interleaved weights).
// mfma(W_frag, A_frag): lane's f32x4 = {i,f,g,o} of one (b,h) cell.
// Wave w: gate quarter wq=w&3 (64 gates), batch half wbh=w>>2 (128 batch).
// LDS per operand: [2 dbuf][2 half][128 rows][64 k] bf16 = 64KB; A+W = 128KB.
// Swizzle: LDS[r][slot] = G[r][slot ^ (r&7)] (16B slots), both sides.

template <int MODE>  // 0: L1 (K=1088, A=[x|h1], writes h1)  1: L2 (K=2048, A=[h1|h2], +proj)
__device__ __forceinline__ void gemm_body(
    int tm, int tn, int t,
    const bf16* __restrict__ P0, const bf16* __restrict__ P1,
    const bf16* __restrict__ Wt, const float* __restrict__ bperm,
    float* __restrict__ ct, bf16* __restrict__ Hout,
    const float* __restrict__ wp, const float* __restrict__ bp,
    float* __restrict__ y,
    bf16* Al, bf16* Wl)
{
  constexpr int KT = (MODE == 0) ? KL1 : KL2;
  constexpr int NT = KT / 64;

  const int tid = threadIdx.x;
  const int lane = tid & 63, w = tid >> 6;
  const int l15 = lane & 15, u = lane >> 4;
  const int wq = w & 3, wbh = w >> 2;

  f32x4 acc[8][4];
  #pragma unroll
  for (int i = 0; i < 8; ++i)
    #pragma unroll
    for (int j = 0; j < 4; ++j) acc[i][j] = (f32x4){0.f, 0.f, 0.f, 0.f};

  // staging geometry
  const int srow = w * 8 + (lane >> 3);           // row within 128-half (+64 for 2nd load)
  const int kx   = (lane & 7) ^ (srow & 7);       // swizzled source 16B-slot
  const int dA   = w * 512 + lane * 8;            // LDS elem offset within half region
  // read geometry (elem offsets of swizzled 16B slot)
  const int jx0 = ((u     ) ^ (l15 & 7)) << 3;    // ks=0
  const int jx1 = ((4 + u ) ^ (l15 & 7)) << 3;    // ks=1

  auto asrc = [&](int row, int kt) -> const bf16* {
    if constexpr (MODE == 0) {
      if (kt == 0) return P0 + (size_t)(tm + row) * 64 + kx * 8;
      return P1 + (size_t)(tm + row) * 1024 + (kt - 1) * 64 + kx * 8;
    } else {
      if (kt < 16) return P0 + (size_t)(tm + row) * 1024 + kt * 64 + kx * 8;
      return P1 + (size_t)(tm + row) * 1024 + (kt - 16) * 64 + kx * 8;
    }
  };
  auto stageA = [&](int buf, int half, int kt) {
    bf16* base = Al + (buf * 2 + half) * 8192;
    gload16(asrc(half * 128 + srow, kt),      base + dA);
    gload16(asrc(half * 128 + srow + 64, kt), base + dA + 4096);
  };
  auto stageW = [&](int buf, int half, int kt) {
    bf16* base = Wl + (buf * 2 + half) * 8192;
    const bf16* g0 = Wt + (size_t)(tn + half * 128 + srow) * KT + kt * 64 + kx * 8;
    const bf16* g1 = Wt + (size_t)(tn + half * 128 + srow + 64) * KT + kt * 64 + kx * 8;
    gload16(g0, base + dA);
    gload16(g1, base + dA + 4096);
  };
  auto rdA = [&](int buf, int bf, int ks) -> bf16x8 {
    return *reinterpret_cast<const bf16x8*>(
        Al + (buf * 2 + wbh) * 8192 + (bf * 16 + l15) * 64 + (ks ? jx1 : jx0));
  };
  auto rdW = [&](int buf, int gf, int ks) -> bf16x8 {
    return *reinterpret_cast<const bf16x8*>(
        Wl + (buf * 2 + (wq >> 1)) * 8192 + ((wq & 1) * 64 + gf * 16 + l15) * 64 + (ks ? jx1 : jx0));
  };

  // prologue: stage K-tile 0 into buf 0 (8 loads/thread in flight)
  stageA(0, 0, 0); stageA(0, 1, 0); stageW(0, 0, 0); stageW(0, 1, 0);

  bf16x8 a_[8], w0_[4], w1_[4];

  for (int kt = 0; kt < NT; ++kt) {
    const int buf = kt & 1, nbuf = buf ^ 1;
    const bool pre = (kt + 1 < NT);

    // flip: this tile's 8 loads were issued one full tile (~620cyc) ago
    WAITV0(); SB(); BAR(); SB();

    // stage ALL of next tile now -> maximal latency cover before next flip
    if (pre) {
      stageA(nbuf, 0, kt + 1); stageA(nbuf, 1, kt + 1);
      stageW(nbuf, 0, kt + 1); stageW(nbuf, 1, kt + 1);
    }
    SB();  // pin staging issue ahead of the compute cluster

    __builtin_amdgcn_s_setprio(1);

    // quadrant 1: (bh0, gf0-1)
    #pragma unroll
    for (int bf = 0; bf < 4; ++bf) { a_[bf * 2] = rdA(buf, bf, 0); a_[bf * 2 + 1] = rdA(buf, bf, 1); }
    #pragma unroll
    for (int g = 0; g < 2; ++g) { w0_[g * 2] = rdW(buf, g, 0); w0_[g * 2 + 1] = rdW(buf, g, 1); }
    #pragma unroll
    for (int bf = 0; bf < 4; ++bf)
      #pragma unroll
      for (int g = 0; g < 2; ++g)
        #pragma unroll
        for (int ks = 0; ks < 2; ++ks)
          acc[bf][g] = __builtin_amdgcn_mfma_f32_16x16x32_bf16(w0_[g * 2 + ks], a_[bf * 2 + ks], acc[bf][g], 0, 0, 0);

    // quadrant 2: (bh0, gf2-3)
    #pragma unroll
    for (int g = 0; g < 2; ++g) { w1_[g * 2] = rdW(buf, 2 + g, 0); w1_[g * 2 + 1] = rdW(buf, 2 + g, 1); }
    #pragma unroll
    for (int bf = 0; bf < 4; ++bf)
      #pragma unroll
      for (int g = 0; g < 2; ++g)
        #pragma unroll
        for (int ks = 0; ks < 2; ++ks)
          acc[bf][2 + g] = __builtin_amdgcn_mfma_f32_16x16x32_bf16(w1_[g * 2 + ks], a_[bf * 2 + ks], acc[bf][2 + g], 0, 0, 0);

    // quadrant 3: (bh1, gf2-3)
    #pragma unroll
    for (int bf = 0; bf < 4; ++bf) { a_[bf * 2] = rdA(buf, 4 + bf, 0); a_[bf * 2 + 1] = rdA(buf, 4 + bf, 1); }
    #pragma unroll
    for (int bf = 0; bf < 4; ++bf)
      #pragma unroll
      for (int g = 0; g < 2; ++g)
        #pragma unroll
        for (int ks = 0; ks < 2; ++ks)
          acc[4 + bf][2 + g] = __builtin_amdgcn_mfma_f32_16x16x32_bf16(w1_[g * 2 + ks], a_[bf * 2 + ks], acc[4 + bf][2 + g], 0, 0, 0);

    // quadrant 4: (bh1, gf0-1) — w0_ held in regs
    #pragma unroll
    for (int bf = 0; bf < 4; ++bf)
      #pragma unroll
      for (int g = 0; g < 2; ++g)
        #pragma unroll
        for (int ks = 0; ks < 2; ++ks)
          acc[4 + bf][g] = __builtin_amdgcn_mfma_f32_16x16x32_bf16(w0_[g * 2 + ks], a_[bf * 2 + ks], acc[4 + bf][g], 0, 0, 0);

    __builtin_amdgcn_s_setprio(0);
    // no end barrier: next flip's barrier serves
  }

  SB(); BAR(); SB();   // all K-loop LDS reads consumed -> safe to reuse LDS

  // ---- fused cell epilogue ----
  bf16* hst = Al + w * 3072;          // per-wave [128 batch][24-padded 16 h] bf16
  const int hb = (tn >> 2) + wq * 16; // wave's h base (16 h values)
  const int bgb = tm + wbh * 128;     // wave's batch base
  float yp[8] = {0.f, 0.f, 0.f, 0.f, 0.f, 0.f, 0.f, 0.f};

  #pragma unroll
  for (int gf = 0; gf < 4; ++gf) {
    int hg = hb + gf * 4 + u;
    f32x4 bv = *reinterpret_cast<const f32x4*>(&bperm[hg * 4]);
    float wph = 0.f;
    if constexpr (MODE == 1) wph = wp[hg];
    #pragma unroll
    for (int bf = 0; bf < 8; ++bf) {
      int bg = bgb + bf * 16 + l15;
      float gi = acc[bf][gf][0] + bv[0];
      float gf_ = acc[bf][gf][1] + bv[1];
      float gg = acc[bf][gf][2] + bv[2];
      float go = acc[bf][gf][3] + bv[3];
      float* cp_ = ct + (size_t)hg * BB + bg;
      float c = *cp_;
      float cn = sigm(gf_) * c + sigm(gi) * tanhf(gg);
      float hn = sigm(go) * tanhf(cn);
      *cp_ = cn;
      hst[(bf * 16 + l15) * 24 + gf * 4 + u] = (bf16)hn;
      if constexpr (MODE == 1) yp[bf] += hn * wph;
    }
  }

  WAITL0(); SB();

  // coalesced H write: wave patch = 128 batch x 16 h
  #pragma unroll
  for (int q = 0; q < 4; ++q) {
    int chunk = q * 64 + lane;        // 0..255
    int row = chunk >> 1, half8 = chunk & 1;
    bf16x8 v = *reinterpret_cast<const bf16x8*>(&hst[row * 24 + half8 * 8]);
    *reinterpret_cast<bf16x8*>(&Hout[(size_t)(bgb + row) * 1024 + hb + half8 * 8]) = v;
  }

  if constexpr (MODE == 1) {
    #pragma unroll
    for (int bf = 0; bf < 8; ++bf) {
      float s = yp[bf];
      s += __shfl_xor(s, 16);
      s += __shfl_xor(s, 32);
      if (lane < 16)
        atomicAdd(&y[(size_t)(bgb + bf * 16 + lane) * TT + t], s);
    }
  } else {
    // init y[:, t] = b_proj (blocks with tn==0 cover all batches)
    if (tn == 0 && tid < 256) y[(size_t)(tm + tid) * TT + t] = bp[0];
  }
}

// Combined dispatch: 256 blocks. XCD-grouped decode so each XCD's L2 caches
// only 2 W-panels: x=bid&7, i=bid>>3: mode=i&1, tm=i>>2, tn = x*2 + ((i>>1)&1).
__global__ __launch_bounds__(512, 2) void step256(
    const bf16* __restrict__ H1in, const bf16* __restrict__ H2in,
    bf16* __restrict__ H1out, bf16* __restrict__ H2out,
    const bf16* __restrict__ X2,
    const bf16* __restrict__ W0, const bf16* __restrict__ W1,
    const float* __restrict__ b0p, const float* __restrict__ b1p,
    float* __restrict__ c1t, float* __restrict__ c2t,
    const float* __restrict__ wp, const float* __restrict__ bp,
    float* __restrict__ y, int t2, int all_l1) {
  __shared__ alignas(16) bf16 Al[32768];
  __shared__ alignas(16) bf16 Wl[32768];
  int bid = (int)blockIdx.x;
  int mode, tmx, tnx;
  if (all_l1) { mode = 0; tmx = bid >> 4; tnx = bid & 15; }
  else {
    int x = bid & 7, i = bid >> 3;
    mode = i & 1; tmx = i >> 2; tnx = x * 2 + ((i >> 1) & 1);
  }
  if (mode == 0) {
    int t1 = t2 + 1;
    if (t1 >= TT) return;
    gemm_body<0>(tmx * 256, tnx * 256, t1, X2 + (size_t)t1 * 2048 * 64, H1in,
                 W0, b0p, c1t, H1out, nullptr, bp, y, Al, Wl);
  } else {
    gemm_body<1>(tmx * 256, tnx * 256, t2, H1in, H2in,
                 W1, b1p, c2t, H2out, wp, nullptr, y, Al, Wl);
  }
}

// ---------------- launch ----------------

extern "C" void kernel_launch(void* const* d_in, const int* in_sizes, int n_in,
                              void* d_out, int out_size, void* d_ws, size_t ws_size,
                              hipStream_t stream) {
  const float* dec   = (const float*)d_in[0];
  const float* ty    = (const float*)d_in[1];
  const float* enc_h = (const float*)d_in[2];
  const float* enc_c = (const float*)d_in[3];
  const float* lec   = (const float*)d_in[4];
  const int*   gid   = (const int*)d_in[5];
  const int*   cp    = (const int*)d_in[6];
  const int*   cct   = (const int*)d_in[7];
  const int*   cpt   = (const int*)d_in[8];
  const int*   ccl   = (const int*)d_in[9];
  const float* gemb  = (const float*)d_in[10];
  const float* ep    = (const float*)d_in[11];
  const float* ect   = (const float*)d_in[12];
  const float* ept   = (const float*)d_in[13];
  const float* ecl   = (const float*)d_in[14];
  const float* Wih0  = (const float*)d_in[15];
  const float* Whh0  = (const float*)d_in[16];
  const float* b0    = (const float*)d_in[17];
  const float* Wih1  = (const float*)d_in[18];
  const float* Whh1  = (const float*)d_in[19];
  const float* b1    = (const float*)d_in[20];
  const float* wp    = (const float*)d_in[21];
  const float* bp    = (const float*)d_in[22];
  float* y = (float*)d_out;

  char* ws = (char*)d_ws;
  bf16* W0    = (bf16*)ws;  ws += (size_t)NG * KL1 * 2;      //  8.9 MB
  bf16* W1    = (bf16*)ws;  ws += (size_t)NG * KL2 * 2;      // 16.8 MB
  bf16* X2    = (bf16*)ws;  ws += (size_t)BB * TT * 64 * 2;  // 25.2 MB  [t][b][64]
  bf16* H1a   = (bf16*)ws;  ws += (size_t)BB * 1024 * 2;     //  4.2 MB
  bf16* H1b   = (bf16*)ws;  ws += (size_t)BB * 1024 * 2;
  bf16* H2a   = (bf16*)ws;  ws += (size_t)BB * 1024 * 2;
  bf16* H2b   = (bf16*)ws;  ws += (size_t)BB * 1024 * 2;
  float* c1t  = (float*)ws; ws += (size_t)BB * 1024 * 4;     //  8.4 MB
  float* c2t  = (float*)ws; ws += (size_t)BB * 1024 * 4;     //  8.4 MB
  float* b0p  = (float*)ws; ws += (size_t)NG * 4;
  float* b1p  = (float*)ws; ws += (size_t)NG * 4;

  build_w0<<<(NG * KL1 + 255) / 256, 256, 0, stream>>>(Wih0, Whh0, W0);
  build_w1<<<(NG * KL2 + 255) / 256, 256, 0, stream>>>(Wih1, Whh1, W1);
  perm_bias<<<NG / 256, 256, 0, stream>>>(b0, b1, b0p, b1p);
  build_x2<<<(BB * TT + 255) / 256, 256, 0, stream>>>(dec, ty, lec, gid, cp, cct, cpt, ccl,
                                                      gemb, ep, ect, ept, ecl, X2);
  init_state<<<(BB * 1024) / 256, 256, 0, stream>>>(enc_h, enc_c, H1b, H2b, c1t, c2t);

  // prologue: L1(0) alone (grid 128). h1(t) in H1[t&1]; h2(t) in H2[t&1].
  step256<<<128, 512, 0, stream>>>(H1b, nullptr, H1a, nullptr, X2, W0, W1,
                                   b0p, b1p, c1t, c2t, wp, bp, y, -1, 1);
  for (int t = 0; t < TT; ++t) {
    bf16* h1i = (t & 1) ? H1b : H1a;
    bf16* h1o = (t & 1) ? H1a : H1b;
    bf16* h2i = (t & 1) ? H2a : H2b;
    bf16* h2o = (t & 1) ? H2b : H2a;
    step256<<<256, 512, 0, stream>>>(h1i, h2i, h1o, h2o, X2, W0, W1,
                                     b0p, b1p, c1t, c2t, wp, bp, y, t, 0);
  }
}